// Round 3
// baseline (511.397 us; speedup 1.0000x reference)
//
#include <hip/hip_runtime.h>
#include <cstdint>

// R9 = R8 fused structure (verified passing, 78.8us kernel) + counted-vmcnt
// pipeline. R8 counters: hbm 26%, VALU 33%, occ 33% -> latency-bound, not a
// roofline. Cause: __syncthreads() drains vmcnt(0) at every barrier (the m97
// structural stall), so the "prefetch" only overlaps the 0.43us compute
// phase and each 32KB chunk load is paid serially (4.9us/chunk observed vs
// 2.6us fair-share transfer). Fix (T3/T4): raw s_barrier with lgkmcnt(0)
// only (LDS-write visibility is all barrier semantics need here -- global
// loads land in registers), depth-2 register prefetch with statically named
// sA/sB sets (rule #20) so the compiler emits counted vmcnt(4) before each
// LDS write. Each load set now gets ~2 chunk periods in flight.
// Data layout, swizzle, compute, reduction, kWTA: bit-identical to R8.

typedef float vf4 __attribute__((ext_vector_type(4)));
typedef float vf2 __attribute__((ext_vector_type(2)));

#define RFN 512
#define TN  32
#define KN  32
#define LN  2048
#define CHUNK 128
#define NITER (LN / CHUNK)   // 16

// ds-writes visible to the workgroup, then barrier; vmcnt stays COUNTED
// (no vmcnt(0) drain -> NT prefetch loads stay in flight across barriers).
#define BARW() do {                                         \
    asm volatile("s_waitcnt lgkmcnt(0)" ::: "memory");      \
    __builtin_amdgcn_s_barrier();                           \
    __builtin_amdgcn_sched_barrier(0);                      \
} while (0)

__global__ __launch_bounds__(512, 4) void column1_fused(
    const float* __restrict__ rec,   // (T=32, C=1, RF=512, L=2048)
    const float* __restrict__ wgt,   // (RF=512, K=32, C=1, L=2048)
    float* __restrict__ out)         // (T=32, 1, K=32, RF=512)
{
    __shared__ __align__(16) float lds[2 * 64 * CHUNK];  // 64 KB dbuf; tail reuses as red
    __shared__ float thr_s[32 * 33];
    __shared__ float nspk_s[32], vals_s[32], cand_s[32], tot_s[32], mask_s[32];

    const int r    = blockIdx.x;     // branch
    const int tid  = threadIdx.x;
    const int lane = tid & 63;
    const int wv   = tid >> 6;       // wave 0..7: splits chunk's 32 quads 8-ways
    const int tg   = lane >> 3;      // 0..7 : owns t in {tg, tg+8, tg+16, tg+24}
    const int kg   = lane & 7;       // 0..7 : owns k in {kg, kg+8, kg+16, kg+24}

    // ---- staging: 4 vf4/thread; rows r0+16s (0..31 rec-t, 32..63 wgt-k), quad c4
    const int c4 = tid & 31;         // quad within 128 floats
    const int r0 = tid >> 5;         // 0..15
    const float* gA[4];              // even-chunk stream: 0,2,4,...
    const float* gB[4];              // odd-chunk stream : 1,3,5,...
    int ldoff[4];
#pragma unroll
    for (int s = 0; s < 4; ++s) {
        const int row = r0 + 16 * s;                // 0..63
        const float* g;
        if (row < 32) g = rec + ((size_t)(row * RFN + r)) * LN + (c4 << 2);
        else          g = wgt + ((size_t)(r * KN + (row - 32))) * LN + (c4 << 2);
        gA[s] = g;
        gB[s] = g + CHUNK;
        // XOR swizzle: quad c4 stored at c4 ^ (row&31) -> conflict-free b128 reads, no pad
        ldoff[s] = row * CHUNK + ((c4 ^ (row & 31)) << 2);
    }

    // depth-2 register prefetch: statically named sets (no runtime indexing)
    vf4 sA[4], sB[4];
#pragma unroll
    for (int s = 0; s < 4; ++s) {
        sA[s] = __builtin_nontemporal_load((const vf4*)gA[s]);  // chunk 0
        gA[s] += 2 * CHUNK;
    }
#pragma unroll
    for (int s = 0; s < 4; ++s) {
        sB[s] = __builtin_nontemporal_load((const vf4*)gB[s]);  // chunk 1
        gB[s] += 2 * CHUNK;
    }

    float acc[4][4];
#pragma unroll
    for (int jt = 0; jt < 4; ++jt)
#pragma unroll
        for (int jk = 0; jk < 4; ++jk) acc[jt][jk] = 0.0f;

    auto compute = [&](const float* buf) {
        const float* rs  = buf;
        const float* wsh = buf + 32 * CHUNK;
#pragma unroll
        for (int q = 0; q < 4; ++q) {
            const int qg = (wv << 2) + q;            // this wave's l-quad (0..31)
            vf4 a[4], b[4];
#pragma unroll
            for (int j = 0; j < 4; ++j) {
                const int row = tg + 8 * j;
                a[j] = *(const vf4*)(rs + row * CHUNK + ((qg ^ (row & 31)) << 2));
            }
#pragma unroll
            for (int j = 0; j < 4; ++j) {
                const int row = kg + 8 * j;          // stored at (32+row); (32+row)&31 == row
                b[j] = *(const vf4*)(wsh + row * CHUNK + ((qg ^ (row & 31)) << 2));
            }
#pragma unroll
            for (int jt = 0; jt < 4; ++jt)
#pragma unroll
                for (int jk = 0; jk < 4; ++jk) {
                    float v0 = fmaf(a[jt].x, b[jk].x, acc[jt][jk]);
                    v0 = fmaf(a[jt].y, b[jk].y, v0);
                    v0 = fmaf(a[jt].z, b[jk].z, v0);
                    acc[jt][jk] = fmaf(a[jt].w, b[jk].w, v0);
                }
        }
    };

    for (int it = 0; it < NITER; it += 2) {
        // ---- even chunk (it): buffer 0, register set A
        {
            float* buf = lds;
#pragma unroll
            for (int s = 0; s < 4; ++s) *(vf4*)(buf + ldoff[s]) = sA[s];  // waits vmcnt(4): B still in flight
            BARW();
            if (it + 2 < NITER) {
#pragma unroll
                for (int s = 0; s < 4; ++s) {
                    sA[s] = __builtin_nontemporal_load((const vf4*)gA[s]);  // chunk it+2
                    gA[s] += 2 * CHUNK;
                }
            }
            compute(buf);
        }
        // ---- odd chunk (it+1): buffer 1, register set B
        {
            float* buf = lds + 64 * CHUNK;
#pragma unroll
            for (int s = 0; s < 4; ++s) *(vf4*)(buf + ldoff[s]) = sB[s];  // waits vmcnt(4): A still in flight
            BARW();
            if (it + 3 < NITER) {
#pragma unroll
                for (int s = 0; s < 4; ++s) {
                    sB[s] = __builtin_nontemporal_load((const vf4*)gB[s]);  // chunk it+3
                    gB[s] += 2 * CHUNK;
                }
            }
            compute(buf);
        }
    }

    __syncthreads();   // all waves done reading buf1 before red overwrites buf0 region

    // ---- cross-wave reduction: 8 sets x 1024 floats = 32 KB into the dbuf region
    float* red = lds;
#pragma unroll
    for (int jt = 0; jt < 4; ++jt)
#pragma unroll
        for (int jk = 0; jk < 4; ++jk)
            red[(wv << 10) + (tg + 8 * jt) * 32 + (kg + 8 * jk)] = acc[jt][jk];
    __syncthreads();

    // ---- each thread sums 2 outputs over the 8 wave-sets, thresholds into thr_s
    const int o2 = tid << 1;                         // 0..1022, flat (t,k) = o2>>5, o2&31
    float pv0 = 0.0f, pv1 = 0.0f;
#pragma unroll
    for (int s = 0; s < 8; ++s) {
        vf2 p = *(const vf2*)(red + (s << 10) + o2);
        pv0 += p.x; pv1 += p.y;
    }
    {
        const float th0 = (pv0 > 20.0f) ? pv0 : 0.0f;  // sf.fire: strictly greater
        const float th1 = (pv1 > 20.0f) ? pv1 : 0.0f;
        thr_s[(o2 >> 5) * 33 + (o2 & 31)]             = th0;
        thr_s[((o2 + 1) >> 5) * 33 + ((o2 + 1) & 31)] = th1;
    }
    __syncthreads();

    // ---- kWTA (verified logic, unchanged)
    if (tid < 32) {
        const int k = tid;
        int ns = 0;
        for (int t = 0; t < 32; ++t) ns += (thr_s[t * 33 + k] > 0.0f) ? 1 : 0;
        int first = 32 - ns; if (first > 31) first = 31;   // clip(T - nspk, 0, T-1)
        const float vf = thr_s[first * 33 + k];
        nspk_s[k] = (float)ns;
        vals_s[k] = vf;
        cand_s[k] = (ns > 0) ? vf : 0.0f;                  // max_t spikes*vals per k
        mask_s[k] = 0.0f;
    }
    __syncthreads();

    if (tid == 0) {
        float vm = 0.0f;
        for (int k = 0; k < 32; ++k) vm = fmaxf(vm, cand_s[k]);
        const float v = vm * 32.0f;                        // trunc.max() * T
        for (int k = 0; k < 32; ++k) tot_s[k] = nspk_s[k] * (vals_s[k] + v);
        // top-4, ties -> lower index (matches lax.top_k); winner valid iff total != 0
        for (int sel = 0; sel < 4; ++sel) {
            int best = 0; float bv = -1.0f;
            for (int k = 0; k < 32; ++k) {
                const float tv = tot_s[k];
                if (tv > bv) { bv = tv; best = k; }
            }
            if (bv > 0.0f) mask_s[best] = 1.0f;
            tot_s[best] = -1.0f;
        }
    }
    __syncthreads();

#pragma unroll
    for (int e = 0; e < 2; ++e) {
        const int oo = o2 + e;
        const int t = oo >> 5, k = oo & 31;
        const float v = (thr_s[t * 33 + k] > 0.0f && mask_s[k] > 0.0f) ? 1.0f : 0.0f;
        __builtin_nontemporal_store(v, out + (size_t)t * (KN * RFN) + k * RFN + r);
    }
}

extern "C" void kernel_launch(void* const* d_in, const int* in_sizes, int n_in,
                              void* d_out, int out_size, void* d_ws, size_t ws_size,
                              hipStream_t stream) {
    const float* rec = (const float*)d_in[0];   // rec_field (32,1,512,2048)
    const float* wgt = (const float*)d_in[1];   // W         (512,32,1,2048)
    // d_in[2] = reward: unused by the forward output; d_ws: unused (fully fused)
    float* out = (float*)d_out;                 // (32,1,32,512)
    column1_fused<<<dim3(RFN), dim3(512), 0, stream>>>(rec, wgt, out);
}

// Round 4
// 501.173 us; speedup vs baseline: 1.0204x; 1.0204x over previous
//
#include <hip/hip_runtime.h>
#include <cstdint>

// R10 = R9's counted-vmcnt pipeline, spill-inducers removed.
// R9 post-mortem: WRITE_SIZE 29MB -> 672MB (= scratch spill/fill storm,
// 512blk x 512thr x 16it x ~80B), dur 78.8 -> 320us. Cause: the [&] compute
// lambda (called 2x/iter inside an asm-fenced region) + extra pointer array
// pushed state through scratch; VGPR_Count pinned at 64 while captures
// round-tripped memory. The overlap THEORY was not falsified.
// R10 changes vs R9: compute body inlined via macro (R8's verified body,
// bit-identical math); single pointer array g[4] stepping +CHUNK per phase;
// depth-2 sA/sB register sets kept (ds_write of sA dependency-waits only on
// sA's loads -> counted vmcnt(4), loads span 2 chunk periods). Sync: raw
// s_barrier + lgkmcnt(0) only (LDS-write visibility is all the barrier needs;
// global loads land in registers) + sched_barrier(0) so post-barrier ds_reads
// can't hoist. Reg tally ~110 < 128 cap -> no spills. Occupancy unchanged
// (LDS-capped at 2 blocks/CU: 70.6KB x2 = 141KB <= 160KB).

typedef float vf4 __attribute__((ext_vector_type(4)));
typedef float vf2 __attribute__((ext_vector_type(2)));

#define RFN 512
#define TN  32
#define KN  32
#define LN  2048
#define CHUNK 128
#define NITER (LN / CHUNK)   // 16

// ds-ops complete & visible, then barrier; vmcnt stays COUNTED (prefetch
// loads remain in flight across the barrier -- the whole point).
#define BARW() do {                                         \
    asm volatile("s_waitcnt lgkmcnt(0)" ::: "memory");      \
    __builtin_amdgcn_s_barrier();                           \
    __builtin_amdgcn_sched_barrier(0);                      \
} while (0)

// R8's verified compute body, macro-inlined (NO lambda: R9's spill storm).
#define COMPUTE(BUF) do {                                                        \
    const float* rs_  = (BUF);                                                   \
    const float* wsh_ = (BUF) + 32 * CHUNK;                                      \
    _Pragma("unroll")                                                            \
    for (int q = 0; q < 4; ++q) {                                                \
        const int qg = (wv << 2) + q;            /* this wave's l-quad */        \
        vf4 a[4], b[4];                                                          \
        _Pragma("unroll")                                                        \
        for (int j = 0; j < 4; ++j) {                                            \
            const int row = tg + 8 * j;                                          \
            a[j] = *(const vf4*)(rs_ + row * CHUNK + ((qg ^ (row & 31)) << 2));  \
        }                                                                        \
        _Pragma("unroll")                                                        \
        for (int j = 0; j < 4; ++j) {                                            \
            const int row = kg + 8 * j;   /* stored at 32+row; (32+row)&31==row */\
            b[j] = *(const vf4*)(wsh_ + row * CHUNK + ((qg ^ (row & 31)) << 2)); \
        }                                                                        \
        _Pragma("unroll")                                                        \
        for (int jt = 0; jt < 4; ++jt)                                           \
            _Pragma("unroll")                                                    \
            for (int jk = 0; jk < 4; ++jk) {                                     \
                float v0 = fmaf(a[jt].x, b[jk].x, acc[jt][jk]);                  \
                v0 = fmaf(a[jt].y, b[jk].y, v0);                                 \
                v0 = fmaf(a[jt].z, b[jk].z, v0);                                 \
                acc[jt][jk] = fmaf(a[jt].w, b[jk].w, v0);                        \
            }                                                                    \
    }                                                                            \
} while (0)

__global__ __launch_bounds__(512, 4) void column1_fused(
    const float* __restrict__ rec,   // (T=32, C=1, RF=512, L=2048)
    const float* __restrict__ wgt,   // (RF=512, K=32, C=1, L=2048)
    float* __restrict__ out)         // (T=32, 1, K=32, RF=512)
{
    __shared__ __align__(16) float lds[2 * 64 * CHUNK];  // 64 KB dbuf; tail reuses as red
    __shared__ float thr_s[32 * 33];
    __shared__ float nspk_s[32], vals_s[32], cand_s[32], tot_s[32], mask_s[32];

    const int r    = blockIdx.x;     // branch
    const int tid  = threadIdx.x;
    const int lane = tid & 63;
    const int wv   = tid >> 6;       // wave 0..7: splits chunk's 32 quads 8-ways
    const int tg   = lane >> 3;      // 0..7 : owns t in {tg, tg+8, tg+16, tg+24}
    const int kg   = lane & 7;       // 0..7 : owns k in {kg, kg+8, kg+16, kg+24}

    // ---- staging: 4 vf4/thread; rows r0+16s (0..31 rec-t, 32..63 wgt-k), quad c4
    const int c4 = tid & 31;         // quad within 128 floats
    const int r0 = tid >> 5;         // 0..15
    const float* g[4];               // single stream, steps +CHUNK per phase
    int ldoff[4];
#pragma unroll
    for (int s = 0; s < 4; ++s) {
        const int row = r0 + 16 * s;                // 0..63
        if (row < 32) g[s] = rec + ((size_t)(row * RFN + r)) * LN + (c4 << 2);
        else          g[s] = wgt + ((size_t)(r * KN + (row - 32))) * LN + (c4 << 2);
        // XOR swizzle: quad c4 stored at c4 ^ (row&31) -> conflict-free b128 reads, no pad
        ldoff[s] = row * CHUNK + ((c4 ^ (row & 31)) << 2);
    }

    // depth-2 register prefetch: statically named sets (rule #20), one pointer stream
    vf4 sA[4], sB[4];
#pragma unroll
    for (int s = 0; s < 4; ++s) {    // chunk 0
        sA[s] = __builtin_nontemporal_load((const vf4*)g[s]);
        g[s] += CHUNK;
    }
#pragma unroll
    for (int s = 0; s < 4; ++s) {    // chunk 1
        sB[s] = __builtin_nontemporal_load((const vf4*)g[s]);
        g[s] += CHUNK;
    }

    float acc[4][4];
#pragma unroll
    for (int jt = 0; jt < 4; ++jt)
#pragma unroll
        for (int jk = 0; jk < 4; ++jk) acc[jt][jk] = 0.0f;

    for (int it = 0; it < NITER; it += 2) {
        // ---- chunk it: buffer 0, register set A
        {
            float* buf = lds;
#pragma unroll
            for (int s = 0; s < 4; ++s) *(vf4*)(buf + ldoff[s]) = sA[s];  // dep-waits sA only: counted vmcnt(4)
            BARW();
            if (it + 2 < NITER) {
#pragma unroll
                for (int s = 0; s < 4; ++s) {
                    sA[s] = __builtin_nontemporal_load((const vf4*)g[s]);  // chunk it+2
                    g[s] += CHUNK;
                }
            }
            COMPUTE(buf);
        }
        // ---- chunk it+1: buffer 1, register set B
        {
            float* buf = lds + 64 * CHUNK;
#pragma unroll
            for (int s = 0; s < 4; ++s) *(vf4*)(buf + ldoff[s]) = sB[s];  // dep-waits sB only: counted vmcnt(4)
            BARW();
            if (it + 3 < NITER) {
#pragma unroll
                for (int s = 0; s < 4; ++s) {
                    sB[s] = __builtin_nontemporal_load((const vf4*)g[s]);  // chunk it+3
                    g[s] += CHUNK;
                }
            }
            COMPUTE(buf);
        }
    }

    __syncthreads();   // all waves' last ds_reads done before red overwrites buf0 region

    // ---- cross-wave reduction: 8 sets x 1024 floats = 32 KB into the dbuf region
    float* red = lds;
#pragma unroll
    for (int jt = 0; jt < 4; ++jt)
#pragma unroll
        for (int jk = 0; jk < 4; ++jk)
            red[(wv << 10) + (tg + 8 * jt) * 32 + (kg + 8 * jk)] = acc[jt][jk];
    __syncthreads();

    // ---- each thread sums 2 outputs over the 8 wave-sets, thresholds into thr_s
    const int o2 = tid << 1;                         // 0..1022, flat (t,k) = o2>>5, o2&31
    float pv0 = 0.0f, pv1 = 0.0f;
#pragma unroll
    for (int s = 0; s < 8; ++s) {
        vf2 p = *(const vf2*)(red + (s << 10) + o2);
        pv0 += p.x; pv1 += p.y;
    }
    {
        const float th0 = (pv0 > 20.0f) ? pv0 : 0.0f;  // sf.fire: strictly greater
        const float th1 = (pv1 > 20.0f) ? pv1 : 0.0f;
        thr_s[(o2 >> 5) * 33 + (o2 & 31)]             = th0;
        thr_s[((o2 + 1) >> 5) * 33 + ((o2 + 1) & 31)] = th1;
    }
    __syncthreads();

    // ---- kWTA (verified logic, unchanged)
    if (tid < 32) {
        const int k = tid;
        int ns = 0;
        for (int t = 0; t < 32; ++t) ns += (thr_s[t * 33 + k] > 0.0f) ? 1 : 0;
        int first = 32 - ns; if (first > 31) first = 31;   // clip(T - nspk, 0, T-1)
        const float vf = thr_s[first * 33 + k];
        nspk_s[k] = (float)ns;
        vals_s[k] = vf;
        cand_s[k] = (ns > 0) ? vf : 0.0f;                  // max_t spikes*vals per k
        mask_s[k] = 0.0f;
    }
    __syncthreads();

    if (tid == 0) {
        float vm = 0.0f;
        for (int k = 0; k < 32; ++k) vm = fmaxf(vm, cand_s[k]);
        const float v = vm * 32.0f;                        // trunc.max() * T
        for (int k = 0; k < 32; ++k) tot_s[k] = nspk_s[k] * (vals_s[k] + v);
        // top-4, ties -> lower index (matches lax.top_k); winner valid iff total != 0
        for (int sel = 0; sel < 4; ++sel) {
            int best = 0; float bv = -1.0f;
            for (int k = 0; k < 32; ++k) {
                const float tv = tot_s[k];
                if (tv > bv) { bv = tv; best = k; }
            }
            if (bv > 0.0f) mask_s[best] = 1.0f;
            tot_s[best] = -1.0f;
        }
    }
    __syncthreads();

#pragma unroll
    for (int e = 0; e < 2; ++e) {
        const int oo = o2 + e;
        const int t = oo >> 5, k = oo & 31;
        const float v = (thr_s[t * 33 + k] > 0.0f && mask_s[k] > 0.0f) ? 1.0f : 0.0f;
        __builtin_nontemporal_store(v, out + (size_t)t * (KN * RFN) + k * RFN + r);
    }
}

extern "C" void kernel_launch(void* const* d_in, const int* in_sizes, int n_in,
                              void* d_out, int out_size, void* d_ws, size_t ws_size,
                              hipStream_t stream) {
    const float* rec = (const float*)d_in[0];   // rec_field (32,1,512,2048)
    const float* wgt = (const float*)d_in[1];   // W         (512,32,1,2048)
    // d_in[2] = reward: unused by the forward output; d_ws: unused (fully fused)
    float* out = (float*)d_out;                 // (32,1,32,512)
    column1_fused<<<dim3(RFN), dim3(512), 0, stream>>>(rec, wgt, out);
}